// Round 19
// baseline (152.397 us; speedup 1.0000x reference)
//
#include <hip/hip_runtime.h>
#include <math.h>

#define NPOS 6400      // H*W
#define BATCH 4
#define CIN 64
#define DI 32          // inter
#define NCHUNK 5       // NC=10 re-tested r17 on permlane body: attn flat, merge +4us -> 5 final
#define CHL (NPOS / NCHUNK)   // 1280
#define KT 64
#define NTILES (CHL / KT)     // 20
#define LOG2E 1.44269504088896f

typedef unsigned short u16;
typedef unsigned int   u32;
typedef __attribute__((ext_vector_type(8))) short short8;
typedef __attribute__((ext_vector_type(4))) float f4v;

__device__ __forceinline__ u32 bfb(float f) {
    return (__float_as_uint(f) + 0x8000u) >> 16;   // bf16 bits, round-half-up
}
__device__ __forceinline__ float fast_exp2(float x) {
    float r;
    asm("v_exp_f32 %0, %1" : "=v"(r) : "v"(x));
    return r;
}
// packed bf16 pair (RNE) -- verified r6: correct, -7% VALUBusy
__device__ __forceinline__ u32 pk_bf16(float lo, float hi) {
    u32 r;
    asm("v_cvt_pk_bf16_f32 %0, %1, %2" : "=v"(r) : "v"(lo), "v"(hi));
    return r;
}
// gfx950 register-pair lane swaps (verified bit-exact r11)
__device__ __forceinline__ void pl32_swap(u32 &a, u32 &b) {
    asm("v_permlane32_swap_b32 %0, %1" : "+v"(a), "+v"(b));
}
__device__ __forceinline__ void pl16_swap(u32 &a, u32 &b) {
    asm("v_permlane16_swap_b32 %0, %1" : "+v"(a), "+v"(b));
}

// ---------------- Kernel A: projections ----------------
// FROZEN: r18-verified (LDS-staged weights; prep history: spill fix r12,
// z=12 split r15, x16 loads r16, LDS broadcast r18 -- diminishing returns,
// parked without counter visibility).
__global__ __launch_bounds__(256) void prep_kernel(
    const float* __restrict__ x,
    const float* __restrict__ w_theta, const float* __restrict__ b_theta,
    const float* __restrict__ w_phi,   const float* __restrict__ b_phi,
    const float* __restrict__ w_g,     const float* __restrict__ b_g,
    u16* __restrict__ thetaT, u16* __restrict__ phiT, u16* __restrict__ gTt)
{
    __shared__ float wlds[8][CIN];   // this block's 8 weight rows (2KB)

    const int t    = threadIdx.x;
    const int b    = blockIdx.y;
    const int mgrp = blockIdx.z >> 2;        // 0..2
    const int o0   = (blockIdx.z & 3) * 8;   // 0,8,16,24
    const int p    = blockIdx.x * 256 + t;

    const float* wm; const float* bs;
    if (mgrp == 0)      { wm = w_theta; bs = b_theta; }
    else if (mgrp == 1) { wm = w_phi;   bs = b_phi;   }
    else                { wm = w_g;     bs = b_g;     }

    // cooperative weight stage: 8 rows x 64 f32 = 128 f4v, threads 0..127
    if (t < 128)
        ((f4v*)wlds)[t] = ((const f4v*)&wm[o0 * CIN])[t];
    __syncthreads();

    const float* xb = x + (size_t)b * CIN * NPOS + p;
    float xr[CIN];
    #pragma unroll
    for (int c = 0; c < CIN; c++) xr[c] = xb[(size_t)c * NPOS];

    float acc[8];
    #pragma unroll
    for (int j = 0; j < 8; j++) acc[j] = bs[o0 + j];

    #pragma unroll
    for (int j = 0; j < 8; j++) {
        const float* wrow = wlds[j];
        float a = acc[j];
        #pragma unroll
        for (int cb = 0; cb < CIN; cb += 4) {
            float4 w4 = *(const float4*)&wrow[cb];   // ds_read_b128 broadcast
            a += w4.x * xr[cb + 0] + w4.y * xr[cb + 1]
               + w4.z * xr[cb + 2] + w4.w * xr[cb + 3];
        }
        acc[j] = a;
    }

    if (mgrp == 2) {
        #pragma unroll
        for (int j = 0; j < 8; j++)
            gTt[((size_t)b * DI + o0 + j) * NPOS + p] = (u16)bfb(acc[j]);
    } else {
        u16* dst = (mgrp == 0 ? thetaT : phiT) + ((size_t)b * NPOS + p) * DI + o0;
        const float sc = (mgrp == 0) ? LOG2E : 1.0f;
        u32 wb[4];
        #pragma unroll
        for (int j = 0; j < 4; j++)
            wb[j] = bfb(acc[2 * j] * sc) | (bfb(acc[2 * j + 1] * sc) << 16);
        *(uint4*)dst = make_uint4(wb[0], wb[1], wb[2], wb[3]);
    }
}

// ---------------- Kernel B: MFMA flash attention, no-max softmax ----------------
// r11-verified body (permlane P-transport, zero LDS, no barriers).
// r19 single change: T5 s_setprio -- priority 1 while issuing MFMA clusters
// (QK and PV/ll), priority 0 during the TRANS/VALU softmax stretch.  Our
// waves are barrier-free and phase-diverse (the m191 +4-7% attn regime, not
// the m190 lockstep-GEMM null regime); the hint lets a wave's MFMAs preempt
// its neighbor's VALU work on the shared SIMD.  No numeric change.
__global__ __launch_bounds__(256) void attn_kernel(
    const u16* __restrict__ thetaT, const u16* __restrict__ phiT,
    const u16* __restrict__ gTt,
    float* __restrict__ Ypart, float* __restrict__ Lpart)
{
    const int tid  = threadIdx.x;
    const int wid  = tid >> 6;
    const int lane = tid & 63;
    const int g    = lane >> 4;
    const int mq   = lane & 15;

    const int b     = blockIdx.y;
    const int cc    = blockIdx.z;
    const int mbase = blockIdx.x * 256 + wid * 64;
    const int c0    = cc * CHL;

    short8 qf[4];
    #pragma unroll
    for (int mt = 0; mt < 4; mt++)
        qf[mt] = *(const short8*)(thetaT + ((size_t)b * NPOS + mbase + mt * 16 + mq) * DI + g * 8);

    f4v o[4][2];
    f4v ll[4];
    #pragma unroll
    for (int mt = 0; mt < 4; mt++) {
        o[mt][0] = (f4v){0.f, 0.f, 0.f, 0.f};
        o[mt][1] = (f4v){0.f, 0.f, 0.f, 0.f};
        ll[mt]   = (f4v){0.f, 0.f, 0.f, 0.f};
    }
    const short8 ones = (short8)(short)0x3F80;   // bf16 1.0 broadcast

    const u16* kbase = phiT + (size_t)b * NPOS * DI;
    const u16* vbase = gTt  + (size_t)b * DI * NPOS;

    // register-double-buffered K/V tile loads
    short8 kf[4], vf[2][2], kn[4], vn[2][2];
    {
        const int n0 = c0;
        #pragma unroll
        for (int nf = 0; nf < 4; nf++)
            kf[nf] = *(const short8*)(kbase + (size_t)(n0 + nf * 16 + mq) * DI + g * 8);
        #pragma unroll
        for (int h = 0; h < 2; h++)
            #pragma unroll
            for (int kc = 0; kc < 2; kc++)
                vf[h][kc] = *(const short8*)(vbase + (size_t)(h * 16 + mq) * NPOS + n0 + kc * 32 + g * 8);
    }

    for (int t = 0; t < NTILES; t++) {
        const int tn = (t + 1 == NTILES) ? 0 : (t + 1);
        const int n1 = c0 + tn * KT;
        #pragma unroll
        for (int nf = 0; nf < 4; nf++)
            kn[nf] = *(const short8*)(kbase + (size_t)(n1 + nf * 16 + mq) * DI + g * 8);
        #pragma unroll
        for (int h = 0; h < 2; h++)
            #pragma unroll
            for (int kc = 0; kc < 2; kc++)
                vn[h][kc] = *(const short8*)(vbase + (size_t)(h * 16 + mq) * NPOS + n1 + kc * 32 + g * 8);

        #pragma unroll
        for (int mt = 0; mt < 4; mt++) {
            f4v s4[4];
            __builtin_amdgcn_s_setprio(1);
            #pragma unroll
            for (int nf = 0; nf < 4; nf++)
                s4[nf] = __builtin_amdgcn_mfma_f32_16x16x32_bf16(
                    kf[nf], qf[mt], (f4v){0.f, 0.f, 0.f, 0.f}, 0, 0, 0);
            __builtin_amdgcn_s_setprio(0);

            // p = exp2(s) raw; pack pairs: pkv[nf][h] = P[q][16nf+4g+2h (,+1)]
            u32 pkv[4][2];
            #pragma unroll
            for (int nf = 0; nf < 4; nf++) {
                pkv[nf][0] = pk_bf16(fast_exp2(s4[nf][0]), fast_exp2(s4[nf][1]));
                pkv[nf][1] = pk_bf16(fast_exp2(s4[nf][2]), fast_exp2(s4[nf][3]));
            }

            // in-register P^T: per (kc,h): PL32 then PL16 -> B-frag registers
            #pragma unroll
            for (int kc = 0; kc < 2; kc++) {
                union { u32 u[4]; short8 s; } pf;
                #pragma unroll
                for (int h = 0; h < 2; h++) {
                    u32 pa = pkv[2 * kc][h];
                    u32 pb = pkv[2 * kc + 1][h];
                    pl32_swap(pa, pb);
                    pl16_swap(pa, pb);
                    pf.u[h]     = pa;   // i1=0 -> regs 0,1
                    pf.u[2 + h] = pb;   // i1=1 -> regs 2,3
                }
                __builtin_amdgcn_s_setprio(1);
                o[mt][0] = __builtin_amdgcn_mfma_f32_16x16x32_bf16(vf[0][kc], pf.s, o[mt][0], 0, 0, 0);
                o[mt][1] = __builtin_amdgcn_mfma_f32_16x16x32_bf16(vf[1][kc], pf.s, o[mt][1], 0, 0, 0);
                ll[mt]   = __builtin_amdgcn_mfma_f32_16x16x32_bf16(ones,      pf.s, ll[mt],   0, 0, 0);
                __builtin_amdgcn_s_setprio(0);
            }
        }

        #pragma unroll
        for (int nf = 0; nf < 4; nf++) kf[nf] = kn[nf];
        #pragma unroll
        for (int h = 0; h < 2; h++) {
            vf[h][0] = vn[h][0];
            vf[h][1] = vn[h][1];
        }
    }

    // epilogue: raw (unnormalized) O^T + l partials (r6-verified layout)
    #pragma unroll
    for (int mt = 0; mt < 4; mt++) {
        size_t rowb = (size_t)(cc * BATCH + b) * NPOS + mbase + mt * 16 + mq;
        float* yp = Ypart + rowb * DI;
        *(f4v*)(yp + 4 * g)      = o[mt][0];
        *(f4v*)(yp + 16 + 4 * g) = o[mt][1];
        if (g == 0) Lpart[rowb] = ll[mt][0];
    }
}

// ---------------- Kernel C: sum partials + out-proj + BN + residual ----------------
// FROZEN: r8-verified block-cooperative LDS-transposed partial sum.
__global__ __launch_bounds__(256) void merge_kernel(
    const float* __restrict__ Ypart, const float* __restrict__ Lpart,
    const float* __restrict__ x,
    const float* __restrict__ w_out, const float* __restrict__ b_out,
    const float* __restrict__ gamma, const float* __restrict__ beta,
    const float* __restrict__ mean,  const float* __restrict__ var,
    float* __restrict__ out)
{
    __shared__ float wsm[CIN * DI];
    __shared__ float shift[CIN];
    __shared__ float ylds[64][DI + 1];   // +1 pad
    __shared__ float rlds[64];

    const int tid = threadIdx.x;
    if (tid < CIN) {
        float inv = gamma[tid] * rsqrtf(var[tid] + 1e-4f);
        shift[tid] = (b_out[tid] - mean[tid]) * inv + beta[tid];
    }
    for (int idx = tid; idx < CIN * DI; idx += 256) {
        int o = idx / DI;
        wsm[idx] = w_out[idx] * (gamma[o] * rsqrtf(var[o] + 1e-4f));
    }

    const int row0 = blockIdx.x * 64;        // block-aligned; never crosses batch
    const int b    = row0 / NPOS;
    const int m0   = row0 - b * NPOS;

    // phase 1: tile = rows m0..m0+63, ch 0..31 = 2048 floats.
    f4v a0 = (f4v){0.f, 0.f, 0.f, 0.f};
    f4v a1 = (f4v){0.f, 0.f, 0.f, 0.f};
    #pragma unroll
    for (int h = 0; h < NCHUNK; h++) {
        const float* base = Ypart + ((size_t)(h * BATCH + b) * NPOS + m0) * DI;
        a0 += *(const f4v*)(base + 4 * tid);
        a1 += *(const f4v*)(base + 1024 + 4 * tid);
    }
    #pragma unroll
    for (int j = 0; j < 4; j++) {
        const int f0 = 4 * tid + j;
        ylds[f0 >> 5][f0 & 31] = a0[j];
        const int f1 = 1024 + 4 * tid + j;
        ylds[f1 >> 5][f1 & 31] = a1[j];
    }
    if (tid < 64) {
        float l = 0.f;
        #pragma unroll
        for (int h = 0; h < NCHUNK; h++)
            l += Lpart[((size_t)h * BATCH + b) * NPOS + m0 + tid];
        rlds[tid] = 1.f / l;
    }
    __syncthreads();

    // phase 2: r0-verbatim projection; wave = one o-quarter, lane = row
    const int oq = tid >> 6;
    const int r  = tid & 63;
    const int m  = m0 + r;

    float y[DI];
    const float rl = rlds[r];
    #pragma unroll
    for (int c = 0; c < DI; c++) y[c] = ylds[r][c] * rl;

    const float* xb = x   + (size_t)b * CIN * NPOS + m;
    float*       ob = out + (size_t)b * CIN * NPOS + m;
    #pragma unroll
    for (int i = 0; i < 16; i++) {
        int o = oq * 16 + i;
        const float* wr = &wsm[o * DI];
        float a2 = 0.f, a3 = 0.f, a4 = 0.f, a5 = 0.f;
        #pragma unroll
        for (int c = 0; c < DI; c += 4) {
            a2 += wr[c + 0] * y[c + 0];
            a3 += wr[c + 1] * y[c + 1];
            a4 += wr[c + 2] * y[c + 2];
            a5 += wr[c + 3] * y[c + 3];
        }
        ob[(size_t)o * NPOS] = (a2 + a3) + (a4 + a5) + shift[o] + xb[(size_t)o * NPOS];
    }
}

extern "C" void kernel_launch(void* const* d_in, const int* in_sizes, int n_in,
                              void* d_out, int out_size, void* d_ws, size_t ws_size,
                              hipStream_t stream) {
    (void)in_sizes; (void)n_in; (void)out_size; (void)ws_size;
    const float* x       = (const float*)d_in[0];
    const float* w_theta = (const float*)d_in[1];
    const float* b_theta = (const float*)d_in[2];
    const float* w_phi   = (const float*)d_in[3];
    const float* b_phi   = (const float*)d_in[4];
    const float* w_g     = (const float*)d_in[5];
    const float* b_g     = (const float*)d_in[6];
    const float* w_out   = (const float*)d_in[7];
    const float* b_out   = (const float*)d_in[8];
    const float* gamma   = (const float*)d_in[9];
    const float* beta    = (const float*)d_in[10];
    const float* mean    = (const float*)d_in[11];
    const float* var     = (const float*)d_in[12];

    float* ws = (float*)d_ws;
    const size_t YN  = (size_t)NCHUNK * BATCH * NPOS * DI;   // 4,096,000 floats
    const size_t LN  = (size_t)NCHUNK * BATCH * NPOS;        //   128,000 floats
    float* Ypart = ws;
    float* Lpart = ws + YN;
    u16* thetaT = (u16*)(ws + YN + LN);
    u16* phiT   = thetaT + (size_t)BATCH * NPOS * DI;
    u16* gTt    = phiT   + (size_t)BATCH * NPOS * DI;

    prep_kernel<<<dim3(NPOS / 256, BATCH, 12), 256, 0, stream>>>(
        x, w_theta, b_theta, w_phi, b_phi, w_g, b_g, thetaT, phiT, gTt);
    attn_kernel<<<dim3(NPOS / 256, BATCH, NCHUNK), 256, 0, stream>>>(
        thetaT, phiT, gTt, Ypart, Lpart);
    merge_kernel<<<dim3((BATCH * NPOS) / 64), 256, 0, stream>>>(
        Ypart, Lpart, x, w_out, b_out, gamma, beta, mean, var, (float*)d_out);
}

// Round 20
// 151.055 us; speedup vs baseline: 1.0089x; 1.0089x over previous
//
#include <hip/hip_runtime.h>
#include <math.h>

#define NPOS 6400      // H*W
#define BATCH 4
#define CIN 64
#define DI 32          // inter
#define NCHUNK 5       // NC=10 tested twice (r2 old body, r17 new body): attn flat, merge +4us
#define CHL (NPOS / NCHUNK)   // 1280
#define KT 64
#define NTILES (CHL / KT)     // 20
#define LOG2E 1.44269504088896f

typedef unsigned short u16;
typedef unsigned int   u32;
typedef __attribute__((ext_vector_type(8))) short short8;
typedef __attribute__((ext_vector_type(4))) float f4v;

__device__ __forceinline__ u32 bfb(float f) {
    return (__float_as_uint(f) + 0x8000u) >> 16;   // bf16 bits, round-half-up
}
__device__ __forceinline__ float fast_exp2(float x) {
    float r;
    asm("v_exp_f32 %0, %1" : "=v"(r) : "v"(x));
    return r;
}
// packed bf16 pair (RNE) -- verified r6: correct, -7% VALUBusy
__device__ __forceinline__ u32 pk_bf16(float lo, float hi) {
    u32 r;
    asm("v_cvt_pk_bf16_f32 %0, %1, %2" : "=v"(r) : "v"(lo), "v"(hi));
    return r;
}
// gfx950 register-pair lane swaps (verified bit-exact r11)
__device__ __forceinline__ void pl32_swap(u32 &a, u32 &b) {
    asm("v_permlane32_swap_b32 %0, %1" : "+v"(a), "+v"(b));
}
__device__ __forceinline__ void pl16_swap(u32 &a, u32 &b) {
    asm("v_permlane16_swap_b32 %0, %1" : "+v"(a), "+v"(b));
}

// ---------------- Kernel A: projections ----------------
// FROZEN r18: LDS-staged weights (history: scratch-spill fix r12, z=12 grid
// split r15, wide scalar loads r16, LDS broadcast r18).
__global__ __launch_bounds__(256) void prep_kernel(
    const float* __restrict__ x,
    const float* __restrict__ w_theta, const float* __restrict__ b_theta,
    const float* __restrict__ w_phi,   const float* __restrict__ b_phi,
    const float* __restrict__ w_g,     const float* __restrict__ b_g,
    u16* __restrict__ thetaT, u16* __restrict__ phiT, u16* __restrict__ gTt)
{
    __shared__ float wlds[8][CIN];   // this block's 8 weight rows (2KB)

    const int t    = threadIdx.x;
    const int b    = blockIdx.y;
    const int mgrp = blockIdx.z >> 2;        // 0..2
    const int o0   = (blockIdx.z & 3) * 8;   // 0,8,16,24
    const int p    = blockIdx.x * 256 + t;

    const float* wm; const float* bs;
    if (mgrp == 0)      { wm = w_theta; bs = b_theta; }
    else if (mgrp == 1) { wm = w_phi;   bs = b_phi;   }
    else                { wm = w_g;     bs = b_g;     }

    // cooperative weight stage: 8 rows x 64 f32 = 128 f4v, threads 0..127
    if (t < 128)
        ((f4v*)wlds)[t] = ((const f4v*)&wm[o0 * CIN])[t];
    __syncthreads();

    const float* xb = x + (size_t)b * CIN * NPOS + p;
    float xr[CIN];
    #pragma unroll
    for (int c = 0; c < CIN; c++) xr[c] = xb[(size_t)c * NPOS];

    float acc[8];
    #pragma unroll
    for (int j = 0; j < 8; j++) acc[j] = bs[o0 + j];

    #pragma unroll
    for (int j = 0; j < 8; j++) {
        const float* wrow = wlds[j];
        float a = acc[j];
        #pragma unroll
        for (int cb = 0; cb < CIN; cb += 4) {
            float4 w4 = *(const float4*)&wrow[cb];   // ds_read_b128 broadcast
            a += w4.x * xr[cb + 0] + w4.y * xr[cb + 1]
               + w4.z * xr[cb + 2] + w4.w * xr[cb + 3];
        }
        acc[j] = a;
    }

    if (mgrp == 2) {
        #pragma unroll
        for (int j = 0; j < 8; j++)
            gTt[((size_t)b * DI + o0 + j) * NPOS + p] = (u16)bfb(acc[j]);
    } else {
        u16* dst = (mgrp == 0 ? thetaT : phiT) + ((size_t)b * NPOS + p) * DI + o0;
        const float sc = (mgrp == 0) ? LOG2E : 1.0f;
        u32 wb[4];
        #pragma unroll
        for (int j = 0; j < 4; j++)
            wb[j] = bfb(acc[2 * j] * sc) | (bfb(acc[2 * j + 1] * sc) << 16);
        *(uint4*)dst = make_uint4(wb[0], wb[1], wb[2], wb[3]);
    }
}

// ---------------- Kernel B: MFMA flash attention, no-max softmax ----------------
// FROZEN r11 body (permlane P-transport, zero LDS, no barriers, 88 VGPR).
// r19's setprio试 removed: null within noise (+4 VGPR), per pre-commitment.
// attn is latency-bound at capacity-pinned ~2 waves/SIMD (VALU 55 / MFMA 22 /
// HBM 8.6%) -- all structural levers tested: occupancy x4 null, P-dbuf null,
// fusion negative, setprio null.  Further gains require a different wave
// architecture (deep pipeline / smaller state), out of scope for this session.
__global__ __launch_bounds__(256) void attn_kernel(
    const u16* __restrict__ thetaT, const u16* __restrict__ phiT,
    const u16* __restrict__ gTt,
    float* __restrict__ Ypart, float* __restrict__ Lpart)
{
    const int tid  = threadIdx.x;
    const int wid  = tid >> 6;
    const int lane = tid & 63;
    const int g    = lane >> 4;
    const int mq   = lane & 15;

    const int b     = blockIdx.y;
    const int cc    = blockIdx.z;
    const int mbase = blockIdx.x * 256 + wid * 64;
    const int c0    = cc * CHL;

    short8 qf[4];
    #pragma unroll
    for (int mt = 0; mt < 4; mt++)
        qf[mt] = *(const short8*)(thetaT + ((size_t)b * NPOS + mbase + mt * 16 + mq) * DI + g * 8);

    f4v o[4][2];
    f4v ll[4];
    #pragma unroll
    for (int mt = 0; mt < 4; mt++) {
        o[mt][0] = (f4v){0.f, 0.f, 0.f, 0.f};
        o[mt][1] = (f4v){0.f, 0.f, 0.f, 0.f};
        ll[mt]   = (f4v){0.f, 0.f, 0.f, 0.f};
    }
    const short8 ones = (short8)(short)0x3F80;   // bf16 1.0 broadcast

    const u16* kbase = phiT + (size_t)b * NPOS * DI;
    const u16* vbase = gTt  + (size_t)b * DI * NPOS;

    // register-double-buffered K/V tile loads
    short8 kf[4], vf[2][2], kn[4], vn[2][2];
    {
        const int n0 = c0;
        #pragma unroll
        for (int nf = 0; nf < 4; nf++)
            kf[nf] = *(const short8*)(kbase + (size_t)(n0 + nf * 16 + mq) * DI + g * 8);
        #pragma unroll
        for (int h = 0; h < 2; h++)
            #pragma unroll
            for (int kc = 0; kc < 2; kc++)
                vf[h][kc] = *(const short8*)(vbase + (size_t)(h * 16 + mq) * NPOS + n0 + kc * 32 + g * 8);
    }

    for (int t = 0; t < NTILES; t++) {
        const int tn = (t + 1 == NTILES) ? 0 : (t + 1);
        const int n1 = c0 + tn * KT;
        #pragma unroll
        for (int nf = 0; nf < 4; nf++)
            kn[nf] = *(const short8*)(kbase + (size_t)(n1 + nf * 16 + mq) * DI + g * 8);
        #pragma unroll
        for (int h = 0; h < 2; h++)
            #pragma unroll
            for (int kc = 0; kc < 2; kc++)
                vn[h][kc] = *(const short8*)(vbase + (size_t)(h * 16 + mq) * NPOS + n1 + kc * 32 + g * 8);

        #pragma unroll
        for (int mt = 0; mt < 4; mt++) {
            f4v s4[4];
            #pragma unroll
            for (int nf = 0; nf < 4; nf++)
                s4[nf] = __builtin_amdgcn_mfma_f32_16x16x32_bf16(
                    kf[nf], qf[mt], (f4v){0.f, 0.f, 0.f, 0.f}, 0, 0, 0);

            // p = exp2(s) raw; pack pairs: pkv[nf][h] = P[q][16nf+4g+2h (,+1)]
            u32 pkv[4][2];
            #pragma unroll
            for (int nf = 0; nf < 4; nf++) {
                pkv[nf][0] = pk_bf16(fast_exp2(s4[nf][0]), fast_exp2(s4[nf][1]));
                pkv[nf][1] = pk_bf16(fast_exp2(s4[nf][2]), fast_exp2(s4[nf][3]));
            }

            // in-register P^T: per (kc,h): PL32 then PL16 -> B-frag registers
            #pragma unroll
            for (int kc = 0; kc < 2; kc++) {
                union { u32 u[4]; short8 s; } pf;
                #pragma unroll
                for (int h = 0; h < 2; h++) {
                    u32 pa = pkv[2 * kc][h];
                    u32 pb = pkv[2 * kc + 1][h];
                    pl32_swap(pa, pb);
                    pl16_swap(pa, pb);
                    pf.u[h]     = pa;   // i1=0 -> regs 0,1
                    pf.u[2 + h] = pb;   // i1=1 -> regs 2,3
                }
                o[mt][0] = __builtin_amdgcn_mfma_f32_16x16x32_bf16(vf[0][kc], pf.s, o[mt][0], 0, 0, 0);
                o[mt][1] = __builtin_amdgcn_mfma_f32_16x16x32_bf16(vf[1][kc], pf.s, o[mt][1], 0, 0, 0);
                ll[mt]   = __builtin_amdgcn_mfma_f32_16x16x32_bf16(ones,      pf.s, ll[mt],   0, 0, 0);
            }
        }

        #pragma unroll
        for (int nf = 0; nf < 4; nf++) kf[nf] = kn[nf];
        #pragma unroll
        for (int h = 0; h < 2; h++) {
            vf[h][0] = vn[h][0];
            vf[h][1] = vn[h][1];
        }
    }

    // epilogue: raw (unnormalized) O^T + l partials (r6-verified layout)
    #pragma unroll
    for (int mt = 0; mt < 4; mt++) {
        size_t rowb = (size_t)(cc * BATCH + b) * NPOS + mbase + mt * 16 + mq;
        float* yp = Ypart + rowb * DI;
        *(f4v*)(yp + 4 * g)      = o[mt][0];
        *(f4v*)(yp + 16 + 4 * g) = o[mt][1];
        if (g == 0) Lpart[rowb] = ll[mt][0];
    }
}

// ---------------- Kernel C: sum partials + out-proj + BN + residual ----------------
// FROZEN r8: block-cooperative LDS-transposed partial sum.
__global__ __launch_bounds__(256) void merge_kernel(
    const float* __restrict__ Ypart, const float* __restrict__ Lpart,
    const float* __restrict__ x,
    const float* __restrict__ w_out, const float* __restrict__ b_out,
    const float* __restrict__ gamma, const float* __restrict__ beta,
    const float* __restrict__ mean,  const float* __restrict__ var,
    float* __restrict__ out)
{
    __shared__ float wsm[CIN * DI];
    __shared__ float shift[CIN];
    __shared__ float ylds[64][DI + 1];   // +1 pad
    __shared__ float rlds[64];

    const int tid = threadIdx.x;
    if (tid < CIN) {
        float inv = gamma[tid] * rsqrtf(var[tid] + 1e-4f);
        shift[tid] = (b_out[tid] - mean[tid]) * inv + beta[tid];
    }
    for (int idx = tid; idx < CIN * DI; idx += 256) {
        int o = idx / DI;
        wsm[idx] = w_out[idx] * (gamma[o] * rsqrtf(var[o] + 1e-4f));
    }

    const int row0 = blockIdx.x * 64;        // block-aligned; never crosses batch
    const int b    = row0 / NPOS;
    const int m0   = row0 - b * NPOS;

    // phase 1: tile = rows m0..m0+63, ch 0..31 = 2048 floats.
    f4v a0 = (f4v){0.f, 0.f, 0.f, 0.f};
    f4v a1 = (f4v){0.f, 0.f, 0.f, 0.f};
    #pragma unroll
    for (int h = 0; h < NCHUNK; h++) {
        const float* base = Ypart + ((size_t)(h * BATCH + b) * NPOS + m0) * DI;
        a0 += *(const f4v*)(base + 4 * tid);
        a1 += *(const f4v*)(base + 1024 + 4 * tid);
    }
    #pragma unroll
    for (int j = 0; j < 4; j++) {
        const int f0 = 4 * tid + j;
        ylds[f0 >> 5][f0 & 31] = a0[j];
        const int f1 = 1024 + 4 * tid + j;
        ylds[f1 >> 5][f1 & 31] = a1[j];
    }
    if (tid < 64) {
        float l = 0.f;
        #pragma unroll
        for (int h = 0; h < NCHUNK; h++)
            l += Lpart[((size_t)h * BATCH + b) * NPOS + m0 + tid];
        rlds[tid] = 1.f / l;
    }
    __syncthreads();

    // phase 2: r0-verbatim projection; wave = one o-quarter, lane = row
    const int oq = tid >> 6;
    const int r  = tid & 63;
    const int m  = m0 + r;

    float y[DI];
    const float rl = rlds[r];
    #pragma unroll
    for (int c = 0; c < DI; c++) y[c] = ylds[r][c] * rl;

    const float* xb = x   + (size_t)b * CIN * NPOS + m;
    float*       ob = out + (size_t)b * CIN * NPOS + m;
    #pragma unroll
    for (int i = 0; i < 16; i++) {
        int o = oq * 16 + i;
        const float* wr = &wsm[o * DI];
        float a2 = 0.f, a3 = 0.f, a4 = 0.f, a5 = 0.f;
        #pragma unroll
        for (int c = 0; c < DI; c += 4) {
            a2 += wr[c + 0] * y[c + 0];
            a3 += wr[c + 1] * y[c + 1];
            a4 += wr[c + 2] * y[c + 2];
            a5 += wr[c + 3] * y[c + 3];
        }
        ob[(size_t)o * NPOS] = (a2 + a3) + (a4 + a5) + shift[o] + xb[(size_t)o * NPOS];
    }
}

extern "C" void kernel_launch(void* const* d_in, const int* in_sizes, int n_in,
                              void* d_out, int out_size, void* d_ws, size_t ws_size,
                              hipStream_t stream) {
    (void)in_sizes; (void)n_in; (void)out_size; (void)ws_size;
    const float* x       = (const float*)d_in[0];
    const float* w_theta = (const float*)d_in[1];
    const float* b_theta = (const float*)d_in[2];
    const float* w_phi   = (const float*)d_in[3];
    const float* b_phi   = (const float*)d_in[4];
    const float* w_g     = (const float*)d_in[5];
    const float* b_g     = (const float*)d_in[6];
    const float* w_out   = (const float*)d_in[7];
    const float* b_out   = (const float*)d_in[8];
    const float* gamma   = (const float*)d_in[9];
    const float* beta    = (const float*)d_in[10];
    const float* mean    = (const float*)d_in[11];
    const float* var     = (const float*)d_in[12];

    float* ws = (float*)d_ws;
    const size_t YN  = (size_t)NCHUNK * BATCH * NPOS * DI;   // 4,096,000 floats
    const size_t LN  = (size_t)NCHUNK * BATCH * NPOS;        //   128,000 floats
    float* Ypart = ws;
    float* Lpart = ws + YN;
    u16* thetaT = (u16*)(ws + YN + LN);
    u16* phiT   = thetaT + (size_t)BATCH * NPOS * DI;
    u16* gTt    = phiT   + (size_t)BATCH * NPOS * DI;

    prep_kernel<<<dim3(NPOS / 256, BATCH, 12), 256, 0, stream>>>(
        x, w_theta, b_theta, w_phi, b_phi, w_g, b_g, thetaT, phiT, gTt);
    attn_kernel<<<dim3(NPOS / 256, BATCH, NCHUNK), 256, 0, stream>>>(
        thetaT, phiT, gTt, Ypart, Lpart);
    merge_kernel<<<dim3((BATCH * NPOS) / 64), 256, 0, stream>>>(
        Ypart, Lpart, x, w_out, b_out, gamma, beta, mean, var, (float*)d_out);
}

// Round 21
// 149.487 us; speedup vs baseline: 1.0195x; 1.0105x over previous
//
#include <hip/hip_runtime.h>
#include <math.h>

#define NPOS 6400      // H*W
#define BATCH 4
#define CIN 64
#define DI 32          // inter
#define NCHUNK 5       // NC=10 tested twice (r2 old body, r17 new body): attn flat, merge +4us
#define CHL (NPOS / NCHUNK)   // 1280
#define KT 64
#define NTILES (CHL / KT)     // 20
#define LOG2E 1.44269504088896f

typedef unsigned short u16;
typedef unsigned int   u32;
typedef __attribute__((ext_vector_type(8))) short short8;
typedef __attribute__((ext_vector_type(4))) float f4v;

__device__ __forceinline__ u32 bfb(float f) {
    return (__float_as_uint(f) + 0x8000u) >> 16;   // bf16 bits, round-half-up
}
__device__ __forceinline__ float fast_exp2(float x) {
    float r;
    asm("v_exp_f32 %0, %1" : "=v"(r) : "v"(x));
    return r;
}
// packed bf16 pair (RNE) -- verified r6: correct, -7% VALUBusy
__device__ __forceinline__ u32 pk_bf16(float lo, float hi) {
    u32 r;
    asm("v_cvt_pk_bf16_f32 %0, %1, %2" : "=v"(r) : "v"(lo), "v"(hi));
    return r;
}
// gfx950 register-pair lane swaps (verified bit-exact r11)
__device__ __forceinline__ void pl32_swap(u32 &a, u32 &b) {
    asm("v_permlane32_swap_b32 %0, %1" : "+v"(a), "+v"(b));
}
__device__ __forceinline__ void pl16_swap(u32 &a, u32 &b) {
    asm("v_permlane16_swap_b32 %0, %1" : "+v"(a), "+v"(b));
}

// ---------------- Kernel A: projections ----------------
// FROZEN r18: LDS-staged weights (history: scratch-spill fix r12, z=12 grid
// split r15, wide scalar loads r16, LDS broadcast r18).
__global__ __launch_bounds__(256) void prep_kernel(
    const float* __restrict__ x,
    const float* __restrict__ w_theta, const float* __restrict__ b_theta,
    const float* __restrict__ w_phi,   const float* __restrict__ b_phi,
    const float* __restrict__ w_g,     const float* __restrict__ b_g,
    u16* __restrict__ thetaT, u16* __restrict__ phiT, u16* __restrict__ gTt)
{
    __shared__ float wlds[8][CIN];   // this block's 8 weight rows (2KB)

    const int t    = threadIdx.x;
    const int b    = blockIdx.y;
    const int mgrp = blockIdx.z >> 2;        // 0..2
    const int o0   = (blockIdx.z & 3) * 8;   // 0,8,16,24
    const int p    = blockIdx.x * 256 + t;

    const float* wm; const float* bs;
    if (mgrp == 0)      { wm = w_theta; bs = b_theta; }
    else if (mgrp == 1) { wm = w_phi;   bs = b_phi;   }
    else                { wm = w_g;     bs = b_g;     }

    // cooperative weight stage: 8 rows x 64 f32 = 128 f4v, threads 0..127
    if (t < 128)
        ((f4v*)wlds)[t] = ((const f4v*)&wm[o0 * CIN])[t];
    __syncthreads();

    const float* xb = x + (size_t)b * CIN * NPOS + p;
    float xr[CIN];
    #pragma unroll
    for (int c = 0; c < CIN; c++) xr[c] = xb[(size_t)c * NPOS];

    float acc[8];
    #pragma unroll
    for (int j = 0; j < 8; j++) acc[j] = bs[o0 + j];

    #pragma unroll
    for (int j = 0; j < 8; j++) {
        const float* wrow = wlds[j];
        float a = acc[j];
        #pragma unroll
        for (int cb = 0; cb < CIN; cb += 4) {
            float4 w4 = *(const float4*)&wrow[cb];   // ds_read_b128 broadcast
            a += w4.x * xr[cb + 0] + w4.y * xr[cb + 1]
               + w4.z * xr[cb + 2] + w4.w * xr[cb + 3];
        }
        acc[j] = a;
    }

    if (mgrp == 2) {
        #pragma unroll
        for (int j = 0; j < 8; j++)
            gTt[((size_t)b * DI + o0 + j) * NPOS + p] = (u16)bfb(acc[j]);
    } else {
        u16* dst = (mgrp == 0 ? thetaT : phiT) + ((size_t)b * NPOS + p) * DI + o0;
        const float sc = (mgrp == 0) ? LOG2E : 1.0f;
        u32 wb[4];
        #pragma unroll
        for (int j = 0; j < 4; j++)
            wb[j] = bfb(acc[2 * j] * sc) | (bfb(acc[2 * j + 1] * sc) << 16);
        *(uint4*)dst = make_uint4(wb[0], wb[1], wb[2], wb[3]);
    }
}

// ---------------- Kernel B: MFMA flash attention, no-max softmax ----------------
// FROZEN r11 body (permlane P-transport, zero LDS, no barriers, 88 VGPR).
// Session-final: latency-bound at capacity-pinned ~2 waves/SIMD (VALU 54 /
// MFMA 21 / HBM 8.6%).  Tested & closed: occupancy x4 (null), P-dbuf (null),
// fusion (-73us), setprio (null), NC rescan (null).  Remaining ideas (deep
// pipeline role-split, 32x32 MFMA re-derivation) are structural rebuilds.
__global__ __launch_bounds__(256) void attn_kernel(
    const u16* __restrict__ thetaT, const u16* __restrict__ phiT,
    const u16* __restrict__ gTt,
    float* __restrict__ Ypart, float* __restrict__ Lpart)
{
    const int tid  = threadIdx.x;
    const int wid  = tid >> 6;
    const int lane = tid & 63;
    const int g    = lane >> 4;
    const int mq   = lane & 15;

    const int b     = blockIdx.y;
    const int cc    = blockIdx.z;
    const int mbase = blockIdx.x * 256 + wid * 64;
    const int c0    = cc * CHL;

    short8 qf[4];
    #pragma unroll
    for (int mt = 0; mt < 4; mt++)
        qf[mt] = *(const short8*)(thetaT + ((size_t)b * NPOS + mbase + mt * 16 + mq) * DI + g * 8);

    f4v o[4][2];
    f4v ll[4];
    #pragma unroll
    for (int mt = 0; mt < 4; mt++) {
        o[mt][0] = (f4v){0.f, 0.f, 0.f, 0.f};
        o[mt][1] = (f4v){0.f, 0.f, 0.f, 0.f};
        ll[mt]   = (f4v){0.f, 0.f, 0.f, 0.f};
    }
    const short8 ones = (short8)(short)0x3F80;   // bf16 1.0 broadcast

    const u16* kbase = phiT + (size_t)b * NPOS * DI;
    const u16* vbase = gTt  + (size_t)b * DI * NPOS;

    // register-double-buffered K/V tile loads
    short8 kf[4], vf[2][2], kn[4], vn[2][2];
    {
        const int n0 = c0;
        #pragma unroll
        for (int nf = 0; nf < 4; nf++)
            kf[nf] = *(const short8*)(kbase + (size_t)(n0 + nf * 16 + mq) * DI + g * 8);
        #pragma unroll
        for (int h = 0; h < 2; h++)
            #pragma unroll
            for (int kc = 0; kc < 2; kc++)
                vf[h][kc] = *(const short8*)(vbase + (size_t)(h * 16 + mq) * NPOS + n0 + kc * 32 + g * 8);
    }

    for (int t = 0; t < NTILES; t++) {
        const int tn = (t + 1 == NTILES) ? 0 : (t + 1);
        const int n1 = c0 + tn * KT;
        #pragma unroll
        for (int nf = 0; nf < 4; nf++)
            kn[nf] = *(const short8*)(kbase + (size_t)(n1 + nf * 16 + mq) * DI + g * 8);
        #pragma unroll
        for (int h = 0; h < 2; h++)
            #pragma unroll
            for (int kc = 0; kc < 2; kc++)
                vn[h][kc] = *(const short8*)(vbase + (size_t)(h * 16 + mq) * NPOS + n1 + kc * 32 + g * 8);

        #pragma unroll
        for (int mt = 0; mt < 4; mt++) {
            f4v s4[4];
            #pragma unroll
            for (int nf = 0; nf < 4; nf++)
                s4[nf] = __builtin_amdgcn_mfma_f32_16x16x32_bf16(
                    kf[nf], qf[mt], (f4v){0.f, 0.f, 0.f, 0.f}, 0, 0, 0);

            // p = exp2(s) raw; pack pairs: pkv[nf][h] = P[q][16nf+4g+2h (,+1)]
            u32 pkv[4][2];
            #pragma unroll
            for (int nf = 0; nf < 4; nf++) {
                pkv[nf][0] = pk_bf16(fast_exp2(s4[nf][0]), fast_exp2(s4[nf][1]));
                pkv[nf][1] = pk_bf16(fast_exp2(s4[nf][2]), fast_exp2(s4[nf][3]));
            }

            // in-register P^T: per (kc,h): PL32 then PL16 -> B-frag registers
            #pragma unroll
            for (int kc = 0; kc < 2; kc++) {
                union { u32 u[4]; short8 s; } pf;
                #pragma unroll
                for (int h = 0; h < 2; h++) {
                    u32 pa = pkv[2 * kc][h];
                    u32 pb = pkv[2 * kc + 1][h];
                    pl32_swap(pa, pb);
                    pl16_swap(pa, pb);
                    pf.u[h]     = pa;   // i1=0 -> regs 0,1
                    pf.u[2 + h] = pb;   // i1=1 -> regs 2,3
                }
                o[mt][0] = __builtin_amdgcn_mfma_f32_16x16x32_bf16(vf[0][kc], pf.s, o[mt][0], 0, 0, 0);
                o[mt][1] = __builtin_amdgcn_mfma_f32_16x16x32_bf16(vf[1][kc], pf.s, o[mt][1], 0, 0, 0);
                ll[mt]   = __builtin_amdgcn_mfma_f32_16x16x32_bf16(ones,      pf.s, ll[mt],   0, 0, 0);
            }
        }

        #pragma unroll
        for (int nf = 0; nf < 4; nf++) kf[nf] = kn[nf];
        #pragma unroll
        for (int h = 0; h < 2; h++) {
            vf[h][0] = vn[h][0];
            vf[h][1] = vn[h][1];
        }
    }

    // epilogue: raw (unnormalized) O^T + l partials (r6-verified layout)
    #pragma unroll
    for (int mt = 0; mt < 4; mt++) {
        size_t rowb = (size_t)(cc * BATCH + b) * NPOS + mbase + mt * 16 + mq;
        float* yp = Ypart + rowb * DI;
        *(f4v*)(yp + 4 * g)      = o[mt][0];
        *(f4v*)(yp + 16 + 4 * g) = o[mt][1];
        if (g == 0) Lpart[rowb] = ll[mt][0];
    }
}

// ---------------- Kernel C: sum partials + out-proj + BN + residual ----------------
// FROZEN r8: block-cooperative LDS-transposed partial sum.
__global__ __launch_bounds__(256) void merge_kernel(
    const float* __restrict__ Ypart, const float* __restrict__ Lpart,
    const float* __restrict__ x,
    const float* __restrict__ w_out, const float* __restrict__ b_out,
    const float* __restrict__ gamma, const float* __restrict__ beta,
    const float* __restrict__ mean,  const float* __restrict__ var,
    float* __restrict__ out)
{
    __shared__ float wsm[CIN * DI];
    __shared__ float shift[CIN];
    __shared__ float ylds[64][DI + 1];   // +1 pad
    __shared__ float rlds[64];

    const int tid = threadIdx.x;
    if (tid < CIN) {
        float inv = gamma[tid] * rsqrtf(var[tid] + 1e-4f);
        shift[tid] = (b_out[tid] - mean[tid]) * inv + beta[tid];
    }
    for (int idx = tid; idx < CIN * DI; idx += 256) {
        int o = idx / DI;
        wsm[idx] = w_out[idx] * (gamma[o] * rsqrtf(var[o] + 1e-4f));
    }

    const int row0 = blockIdx.x * 64;        // block-aligned; never crosses batch
    const int b    = row0 / NPOS;
    const int m0   = row0 - b * NPOS;

    // phase 1: tile = rows m0..m0+63, ch 0..31 = 2048 floats.
    f4v a0 = (f4v){0.f, 0.f, 0.f, 0.f};
    f4v a1 = (f4v){0.f, 0.f, 0.f, 0.f};
    #pragma unroll
    for (int h = 0; h < NCHUNK; h++) {
        const float* base = Ypart + ((size_t)(h * BATCH + b) * NPOS + m0) * DI;
        a0 += *(const f4v*)(base + 4 * tid);
        a1 += *(const f4v*)(base + 1024 + 4 * tid);
    }
    #pragma unroll
    for (int j = 0; j < 4; j++) {
        const int f0 = 4 * tid + j;
        ylds[f0 >> 5][f0 & 31] = a0[j];
        const int f1 = 1024 + 4 * tid + j;
        ylds[f1 >> 5][f1 & 31] = a1[j];
    }
    if (tid < 64) {
        float l = 0.f;
        #pragma unroll
        for (int h = 0; h < NCHUNK; h++)
            l += Lpart[((size_t)h * BATCH + b) * NPOS + m0 + tid];
        rlds[tid] = 1.f / l;
    }
    __syncthreads();

    // phase 2: r0-verbatim projection; wave = one o-quarter, lane = row
    const int oq = tid >> 6;
    const int r  = tid & 63;
    const int m  = m0 + r;

    float y[DI];
    const float rl = rlds[r];
    #pragma unroll
    for (int c = 0; c < DI; c++) y[c] = ylds[r][c] * rl;

    const float* xb = x   + (size_t)b * CIN * NPOS + m;
    float*       ob = out + (size_t)b * CIN * NPOS + m;
    #pragma unroll
    for (int i = 0; i < 16; i++) {
        int o = oq * 16 + i;
        const float* wr = &wsm[o * DI];
        float a2 = 0.f, a3 = 0.f, a4 = 0.f, a5 = 0.f;
        #pragma unroll
        for (int c = 0; c < DI; c += 4) {
            a2 += wr[c + 0] * y[c + 0];
            a3 += wr[c + 1] * y[c + 1];
            a4 += wr[c + 2] * y[c + 2];
            a5 += wr[c + 3] * y[c + 3];
        }
        ob[(size_t)o * NPOS] = (a2 + a3) + (a4 + a5) + shift[o] + xb[(size_t)o * NPOS];
    }
}

extern "C" void kernel_launch(void* const* d_in, const int* in_sizes, int n_in,
                              void* d_out, int out_size, void* d_ws, size_t ws_size,
                              hipStream_t stream) {
    (void)in_sizes; (void)n_in; (void)out_size; (void)ws_size;
    const float* x       = (const float*)d_in[0];
    const float* w_theta = (const float*)d_in[1];
    const float* b_theta = (const float*)d_in[2];
    const float* w_phi   = (const float*)d_in[3];
    const float* b_phi   = (const float*)d_in[4];
    const float* w_g     = (const float*)d_in[5];
    const float* b_g     = (const float*)d_in[6];
    const float* w_out   = (const float*)d_in[7];
    const float* b_out   = (const float*)d_in[8];
    const float* gamma   = (const float*)d_in[9];
    const float* beta    = (const float*)d_in[10];
    const float* mean    = (const float*)d_in[11];
    const float* var     = (const float*)d_in[12];

    float* ws = (float*)d_ws;
    const size_t YN  = (size_t)NCHUNK * BATCH * NPOS * DI;   // 4,096,000 floats
    const size_t LN  = (size_t)NCHUNK * BATCH * NPOS;        //   128,000 floats
    float* Ypart = ws;
    float* Lpart = ws + YN;
    u16* thetaT = (u16*)(ws + YN + LN);
    u16* phiT   = thetaT + (size_t)BATCH * NPOS * DI;
    u16* gTt    = phiT   + (size_t)BATCH * NPOS * DI;

    prep_kernel<<<dim3(NPOS / 256, BATCH, 12), 256, 0, stream>>>(
        x, w_theta, b_theta, w_phi, b_phi, w_g, b_g, thetaT, phiT, gTt);
    attn_kernel<<<dim3(NPOS / 256, BATCH, NCHUNK), 256, 0, stream>>>(
        thetaT, phiT, gTt, Ypart, Lpart);
    merge_kernel<<<dim3((BATCH * NPOS) / 64), 256, 0, stream>>>(
        Ypart, Lpart, x, w_out, b_out, gamma, beta, mean, var, (float*)d_out);
}